// Round 4
// baseline (582.396 us; speedup 1.0000x reference)
//
#include <hip/hip_runtime.h>

typedef __bf16 bf16;
typedef __bf16 bf16x4 __attribute__((ext_vector_type(4)));
typedef __bf16 bf16x8 __attribute__((ext_vector_type(8)));
typedef float f32x4 __attribute__((ext_vector_type(4)));

#define M_TOT 65536   // B*T
#define K_TOT 1024    // D_IN
#define N_TOT 512     // H1
#define T_SEQ 2048
#define NB 32

// ---------------------------------------------------------------------------
// async global->LDS, 16B per lane. LDS dest = wave-uniform base + lane*16.
// ---------------------------------------------------------------------------
__device__ __forceinline__ void async16(const void* g, void* l) {
    __builtin_amdgcn_global_load_lds(
        (const __attribute__((address_space(1))) unsigned int*)g,
        (__attribute__((address_space(3))) unsigned int*)l, 16, 0, 0);
}

// ---------------------------------------------------------------------------
// Kernel 0a: W1 [1024,512] fp32 -> W1T [512,1024] bf16 (transposed)
// ---------------------------------------------------------------------------
__global__ __launch_bounds__(256) void transpose_w1(const float* __restrict__ W1,
                                                    bf16* __restrict__ W1T) {
    __shared__ float tile[32][33];
    const int t = threadIdx.x;
    const int k0 = blockIdx.x * 32;
    const int n0 = blockIdx.y * 32;
#pragma unroll
    for (int p = 0; p < 4; p++) {
        int kl = p * 8 + (t >> 5);
        int nl = t & 31;
        tile[kl][nl] = W1[(k0 + kl) * 512 + n0 + nl];
    }
    __syncthreads();
#pragma unroll
    for (int p = 0; p < 4; p++) {
        int nl = p * 8 + (t >> 5);
        int kl = t & 31;
        W1T[(n0 + nl) * 1024 + k0 + kl] = (bf16)tile[kl][nl];
    }
}

// ---------------------------------------------------------------------------
// Kernel 0b: fold layers 2+3: v[h] = sum_c W2[h][c]*W3[c]; v[512] = b2.W3+b3
// ---------------------------------------------------------------------------
__global__ __launch_bounds__(512) void make_v(const float* __restrict__ W2,
                                              const float* __restrict__ b2,
                                              const float* __restrict__ W3,
                                              const float* __restrict__ b3,
                                              float* __restrict__ v) {
    const int t = threadIdx.x;
    float s = 0.f;
#pragma unroll
    for (int c = 0; c < 32; c++) s += W2[t * 32 + c] * W3[c];
    v[t] = s;
    if (t == 0) {
        float cc = b3[0];
        for (int c = 0; c < 32; c++) cc += b2[c] * W3[c];
        v[512] = cc;
    }
}

// ---------------------------------------------------------------------------
// Kernel 1: GEMM + relu + partial dot, N-split by 4.
// Block (nq, mt): 256 thr / 4 waves (2wm x 2wn); tile 128 rows x 128 cols.
// A: fragments DIRECT from global fp32 (L1-served; no LDS round-trip), cvt
//    to bf16 in-reg. B: async16 -> LDS, XOR swizzle, double buffer 2x16 KB.
// Occupancy target: 3 blocks/CU (12 waves) via small LDS + <=170 VGPR.
// Output: partial[nq][m] = sum_{h in nq-slice} relu(h1)*v[h]  (no atomics).
// ---------------------------------------------------------------------------
__device__ __forceinline__ int sw_idx(int row, int e) {  // elem idx into [row][64]
    return row * 64 + (((e >> 3) ^ (row & 7)) << 3) + (e & 7);
}

__global__ __launch_bounds__(256, 3) void gemm_part(const float* __restrict__ A,
                                                    const bf16* __restrict__ W1T,
                                                    const float* __restrict__ b1,
                                                    const float* __restrict__ v,
                                                    float* __restrict__ partial) {
    __shared__ bf16 Bs[2][128 * 64];   // 2 x 16 KB
    __shared__ float part[128][2];

    const int t = threadIdx.x;
    const int wave = t >> 6, lane = t & 63;
    const int lq = lane >> 4, l15 = lane & 15;
    const int wm = wave >> 1, wn = wave & 1;   // 2 x 2 wave grid, wave tile 64x64
    const int nq = blockIdx.x;                 // 0..3  n-quarter
    const int m0 = blockIdx.y * 128;
    const int n0 = nq * 128;

    // B async staging: per wave 4 issues; issue j covers local rows
    // wave*32 + j*8 + (lane>>3), 16B chunk (lane&7) XOR'd for swizzle.
    const int blr = (lane >> 3);               // 0..7
    const int blc = (lane & 7) ^ blr;          // swizzled chunk
    const bf16* bgp = W1T + (size_t)(n0 + wave * 32 + blr) * K_TOT + blc * 8;

    // A fragment base: row = m0 + wm*64 + mi*16 + l15 ; k = k0 + kk + lq*8
    const float* agp = A + (size_t)(m0 + wm * 64 + l15) * K_TOT + lq * 8;

    f32x4 acc[4][4] = {};

    auto asyncB = [&](int k0, int b) {
        bf16* bs = Bs[b];
#pragma unroll
        for (int j = 0; j < 4; j++)
            async16(bgp + k0 + (size_t)j * 8 * K_TOT,
                    bs + (wave * 32 + j * 8) * 64);
    };

    asyncB(0, 0);
    __syncthreads();   // B(0) resident

#pragma unroll 1
    for (int k = 0; k < 16; k++) {
        const int buf = k & 1;
        const int k0 = k * 64;
        if (k < 15) asyncB(k0 + 64, buf ^ 1);   // prefetch: drained at NEXT barrier
#pragma unroll
        for (int kk = 0; kk < 64; kk += 32) {
            // A fragments direct from global (fp32 -> bf16)
            bf16x8 af[4];
#pragma unroll
            for (int mi = 0; mi < 4; mi++) {
                const float* p = agp + (size_t)(mi * 16) * K_TOT + k0 + kk;
                float4 x = *(const float4*)(p);
                float4 y = *(const float4*)(p + 4);
                bf16x8 f;
                f[0] = (bf16)x.x; f[1] = (bf16)x.y; f[2] = (bf16)x.z; f[3] = (bf16)x.w;
                f[4] = (bf16)y.x; f[5] = (bf16)y.y; f[6] = (bf16)y.z; f[7] = (bf16)y.w;
                af[mi] = f;
            }
            bf16x8 bfv[4];
            const int e = kk + lq * 8;
#pragma unroll
            for (int ni = 0; ni < 4; ni++)
                bfv[ni] = *(const bf16x8*)(&Bs[buf][sw_idx(wn * 64 + ni * 16 + l15, e)]);
#pragma unroll
            for (int mi = 0; mi < 4; mi++)
#pragma unroll
                for (int ni = 0; ni < 4; ni++)
                    acc[mi][ni] = __builtin_amdgcn_mfma_f32_16x16x32_bf16(
                        af[mi], bfv[ni], acc[mi][ni], 0, 0, 0);
        }
        __syncthreads();   // all waves done reading Bs[buf]; B(k+1) drained
    }

    // ---- Epilogue: per-row partial = sum over this block's 128 cols ----
    float bb[4], vv[4];
#pragma unroll
    for (int ni = 0; ni < 4; ni++) {
        int col = n0 + wn * 64 + ni * 16 + l15;
        bb[ni] = b1[col];
        vv[ni] = v[col];
    }

#pragma unroll
    for (int mi = 0; mi < 4; mi++) {
#pragma unroll
        for (int r = 0; r < 4; r++) {
            float s = 0.f;
#pragma unroll
            for (int ni = 0; ni < 4; ni++)
                s += fmaxf(acc[mi][ni][r] + bb[ni], 0.f) * vv[ni];
            s += __shfl_xor(s, 1);
            s += __shfl_xor(s, 2);
            s += __shfl_xor(s, 4);
            s += __shfl_xor(s, 8);
            if (l15 == 0) part[wm * 64 + mi * 16 + lq * 4 + r][wn] = s;
        }
    }
    __syncthreads();
    if (t < 128)
        partial[(size_t)nq * M_TOT + m0 + t] = part[t][0] + part[t][1];
}

// ---------------------------------------------------------------------------
// Kernel 2: logits[m] = sigmoid(sum_q partial[q][m] + c)
// ---------------------------------------------------------------------------
__global__ __launch_bounds__(256) void sum_sigmoid(const float* __restrict__ partial,
                                                   const float* __restrict__ v,
                                                   float* __restrict__ logits) {
    const int m = blockIdx.x * 256 + threadIdx.x;
    const float c = v[512];
    float s = partial[m] + partial[M_TOT + m] + partial[2 * M_TOT + m] +
              partial[3 * M_TOT + m] + c;
    logits[m] = 1.f / (1.f + __expf(-s));
}

// ---------------------------------------------------------------------------
// Kernel 3: per-sample ragged top-k mean (exact; binary search on float bits).
// ---------------------------------------------------------------------------
__global__ __launch_bounds__(256) void topk_mean(const float* __restrict__ logits,
                                                 const int* __restrict__ seq_len,
                                                 float* __restrict__ out) {
    __shared__ float vals[T_SEQ];
    __shared__ int redi[4];
    __shared__ float redf[4];
    const int b = blockIdx.x, t = threadIdx.x;
    const int lane = t & 63, wave = t >> 6;
    const int L = seq_len[b];
    const int k = (L >> 4) + 1;
    const float* p = logits + b * T_SEQ;
    for (int i = t; i < L; i += 256) vals[i] = p[i];
    __syncthreads();

    unsigned lo = 0u, hi = 0x3f800000u;  // (0, 1.0]
    while (lo < hi) {
        unsigned mid = lo + ((hi - lo + 1) >> 1);
        float thr = __uint_as_float(mid);
        int cnt = 0;
        for (int i = t; i < L; i += 256) cnt += (vals[i] >= thr) ? 1 : 0;
#pragma unroll
        for (int m = 32; m >= 1; m >>= 1) cnt += __shfl_xor(cnt, m);
        if (lane == 0) redi[wave] = cnt;
        __syncthreads();
        int total = redi[0] + redi[1] + redi[2] + redi[3];
        __syncthreads();
        if (total >= k) lo = mid; else hi = mid - 1;
    }
    const float thr = __uint_as_float(lo);

    int cnt = 0; float sum = 0.f;
    for (int i = t; i < L; i += 256) {
        float x = vals[i];
        if (x > thr) { cnt += 1; sum += x; }
    }
#pragma unroll
    for (int m = 32; m >= 1; m >>= 1) { cnt += __shfl_xor(cnt, m); sum += __shfl_xor(sum, m); }
    if (lane == 0) { redi[wave] = cnt; redf[wave] = sum; }
    __syncthreads();
    if (t == 0) {
        int cgt = redi[0] + redi[1] + redi[2] + redi[3];
        float sgt = redf[0] + redf[1] + redf[2] + redf[3];
        out[b] = (sgt + (float)(k - cgt) * thr) / (float)k;
    }
}

// ---------------------------------------------------------------------------
extern "C" void kernel_launch(void* const* d_in, const int* in_sizes, int n_in,
                              void* d_out, int out_size, void* d_ws, size_t ws_size,
                              hipStream_t stream) {
    const float* avf = (const float*)d_in[0];
    const float* W1  = (const float*)d_in[1];
    const float* b1  = (const float*)d_in[2];
    const float* W2  = (const float*)d_in[3];
    const float* b2  = (const float*)d_in[4];
    const float* W3  = (const float*)d_in[5];
    const float* b3  = (const float*)d_in[6];
    const int* seq_len = (const int*)d_in[7];
    float* out = (float*)d_out;

    char* ws = (char*)d_ws;
    bf16*  W1T    = (bf16*)ws;                          // 1 MB @ 0
    float* v      = (float*)(ws + (1 << 20));           // 513 floats
    float* logits = (float*)(ws + (1 << 20) + (1 << 16)); // 256 KB
    float* partial= (float*)(ws + (2 << 20));           // 4 x 65536 fp32 = 1 MB

    transpose_w1<<<dim3(32, 16), 256, 0, stream>>>(W1, W1T);
    make_v<<<1, 512, 0, stream>>>(W2, b2, W3, b3, v);
    gemm_part<<<dim3(4, 512), 256, 0, stream>>>(avf, W1T, b1, v, partial);
    sum_sigmoid<<<M_TOT / 256, 256, 0, stream>>>(partial, v, logits);
    topk_mean<<<NB, 256, 0, stream>>>(logits, seq_len, out);
}

// Round 5
// 486.803 us; speedup vs baseline: 1.1964x; 1.1964x over previous
//
#include <hip/hip_runtime.h>

typedef __bf16 bf16;
typedef __bf16 bf16x4 __attribute__((ext_vector_type(4)));
typedef __bf16 bf16x8 __attribute__((ext_vector_type(8)));
typedef float f32x4 __attribute__((ext_vector_type(4)));

#define M_TOT 65536   // B*T
#define K_TOT 1024    // D_IN
#define N_TOT 512     // H1
#define T_SEQ 2048
#define NB 32

// ---------------------------------------------------------------------------
// async global->LDS, 16B per lane. LDS dest must be WAVE-UNIFORM base;
// HW writes lane i at base + i*16.
// ---------------------------------------------------------------------------
__device__ __forceinline__ void async16(const void* g, void* l) {
    __builtin_amdgcn_global_load_lds(
        (const __attribute__((address_space(1))) unsigned int*)g,
        (__attribute__((address_space(3))) unsigned int*)l, 16, 0, 0);
}

// ---------------------------------------------------------------------------
// Kernel 0a: W1 [1024,512] fp32 -> W1T [512,1024] bf16 (transposed)
// ---------------------------------------------------------------------------
__global__ __launch_bounds__(256) void transpose_w1(const float* __restrict__ W1,
                                                    bf16* __restrict__ W1T) {
    __shared__ float tile[32][33];
    const int t = threadIdx.x;
    const int k0 = blockIdx.x * 32;
    const int n0 = blockIdx.y * 32;
#pragma unroll
    for (int p = 0; p < 4; p++) {
        int kl = p * 8 + (t >> 5);
        int nl = t & 31;
        tile[kl][nl] = W1[(k0 + kl) * 512 + n0 + nl];
    }
    __syncthreads();
#pragma unroll
    for (int p = 0; p < 4; p++) {
        int nl = p * 8 + (t >> 5);
        int kl = t & 31;
        W1T[(n0 + nl) * 1024 + k0 + kl] = (bf16)tile[kl][nl];
    }
}

// ---------------------------------------------------------------------------
// Kernel 0b: fold layers 2+3: v[h] = sum_c W2[h][c]*W3[c]; v[512] = b2.W3+b3
// ---------------------------------------------------------------------------
__global__ __launch_bounds__(512) void make_v(const float* __restrict__ W2,
                                              const float* __restrict__ b2,
                                              const float* __restrict__ W3,
                                              const float* __restrict__ b3,
                                              float* __restrict__ v) {
    const int t = threadIdx.x;
    float s = 0.f;
#pragma unroll
    for (int c = 0; c < 32; c++) s += W2[t * 32 + c] * W3[c];
    v[t] = s;
    if (t == 0) {
        float cc = b3[0];
        for (int c = 0; c < 32; c++) cc += b2[c] * W3[c];
        v[512] = cc;
    }
}

// ---------------------------------------------------------------------------
// Kernel 1 (fused): per block 64 rows x FULL N=512, BK=32, double-buffered.
// 512 thr = 8 waves, each wave owns a 64-col slice (wave tile 64x64,
// acc 4x4 = 64 AGPR). A staged via LDS (read ONCE from HBM), B via async16.
// Early-exit: block's 64 rows lie inside one sample; rows >= seq_len[b]
// never feed the top-k, so whole dead blocks skip (~48% of work).
// Swizzle: chunk' = chunk ^ ((r ^ (r>>2)) & 3) on 16B chunks of 64B rows
// -> exact 2-way bank aliasing (free) on all ds_read_b128 / writes.
// Budget: 74 KB LDS, <=64 VGPR + 64 AGPR -> 2 blocks/CU, 4 waves/SIMD.
// ---------------------------------------------------------------------------
__global__ __launch_bounds__(512, 4) void gemm_fused(const float* __restrict__ A,
                                                     const bf16* __restrict__ W1T,
                                                     const float* __restrict__ b1,
                                                     const float* __restrict__ v,
                                                     const int* __restrict__ seq_len,
                                                     float* __restrict__ logits) {
    __shared__ bf16 As[2][64 * 32];    // 2 x 4 KB
    __shared__ bf16 Bs[2][512 * 32];   // 2 x 32 KB
    __shared__ float part[64][8];      // 2 KB

    const int m0 = blockIdx.x * 64;
    const int smp = m0 >> 11;          // sample index (2048 rows per sample)
    const int L = seq_len[smp];
    if ((m0 & 2047) >= L) return;      // dead block: rows never read by top-k

    const int t = threadIdx.x;
    const int wave = t >> 6, lane = t & 63;
    const int q = lane >> 4, l15 = lane & 15;

    // A staging: thread t -> row t>>3 (0..63), float4 #(t&7). One float4/iter.
    const int ar = t >> 3, a4 = t & 7;
    const float* agp = A + (size_t)(m0 + ar) * K_TOT + a4 * 4;
    const int aoff = ar * 32 + (((a4 >> 1) ^ ((ar ^ (ar >> 2)) & 3)) << 3) + (a4 & 1) * 4;

    // B async staging: wave covers n-rows [wave*64, +64) in 4 issues of 16.
    // Global chunk XOR-permuted so linear LDS dest lands swizzled;
    // permutation reduces to a lane-only constant (j,wave terms vanish mod 4).
    const int cg = (lane & 3) ^ ((lane >> 2) & 3) ^ ((lane >> 4) & 3);
    const bf16* bgp = W1T + (size_t)(wave * 64 + (lane >> 2)) * K_TOT + cg * 8;

    // Fragment chunk (A and B reads): q ^ sw(row), row-dependence reduces to l15.
    const int fch = q ^ ((l15 ^ (l15 >> 2)) & 3);

    f32x4 acc[4][4] = {};
    float4 av;

    auto loadA = [&](int k0) { av = *(const float4*)(agp + k0); };
    auto asyncB = [&](int k0, int b) {
#pragma unroll
        for (int j = 0; j < 4; j++)
            async16(bgp + k0 + (size_t)j * 16 * K_TOT,
                    &Bs[b][(wave * 64 + j * 16) * 32]);
    };
    auto writeA = [&](int b) {
        bf16x4 w;
        w[0] = (bf16)av.x; w[1] = (bf16)av.y; w[2] = (bf16)av.z; w[3] = (bf16)av.w;
        *(bf16x4*)(&As[b][aoff]) = w;
    };

    loadA(0);
    asyncB(0, 0);
    writeA(0);
    __syncthreads();

#pragma unroll 1
    for (int k = 0; k < 32; k++) {
        const int buf = k & 1, nxt = buf ^ 1;
        if (k < 31) {
            loadA((k + 1) * 32);       // 1 global_load_dwordx4, overlaps MFMA
            asyncB((k + 1) * 32, nxt); // 4 global_load_lds_dwordx4
        }
        // MFMA phase: 8 ds_read_b128 + 16 MFMA
        bf16x8 af[4], bfv[4];
#pragma unroll
        for (int mi = 0; mi < 4; mi++)
            af[mi] = *(const bf16x8*)(&As[buf][(mi * 16 + l15) * 32 + fch * 8]);
#pragma unroll
        for (int ni = 0; ni < 4; ni++)
            bfv[ni] = *(const bf16x8*)(&Bs[buf][(wave * 64 + ni * 16 + l15) * 32 + fch * 8]);
#pragma unroll
        for (int mi = 0; mi < 4; mi++)
#pragma unroll
            for (int ni = 0; ni < 4; ni++)
                acc[mi][ni] = __builtin_amdgcn_mfma_f32_16x16x32_bf16(
                    af[mi], bfv[ni], acc[mi][ni], 0, 0, 0);
        if (k < 31) writeA(nxt);       // waits av (vmcnt leaves asyncB in flight)
        __syncthreads();
    }

    // ---- Epilogue: logit[m] = sigmoid( sum_cols relu(acc + b1)*v + c ) ----
    float bb[4], vv[4];
#pragma unroll
    for (int ni = 0; ni < 4; ni++) {
        int col = wave * 64 + ni * 16 + l15;
        bb[ni] = b1[col];
        vv[ni] = v[col];
    }
    const float cconst = v[512];

#pragma unroll
    for (int mi = 0; mi < 4; mi++) {
#pragma unroll
        for (int r = 0; r < 4; r++) {
            float s = 0.f;
#pragma unroll
            for (int ni = 0; ni < 4; ni++)
                s += fmaxf(acc[mi][ni][r] + bb[ni], 0.f) * vv[ni];
            s += __shfl_xor(s, 1);
            s += __shfl_xor(s, 2);
            s += __shfl_xor(s, 4);
            s += __shfl_xor(s, 8);
            if (l15 == 0) part[mi * 16 + q * 4 + r][wave] = s;
        }
    }
    __syncthreads();
    if (t < 64) {
        float s = cconst;
#pragma unroll
        for (int w = 0; w < 8; w++) s += part[t][w];
        logits[m0 + t] = 1.f / (1.f + __expf(-s));
    }
}

// ---------------------------------------------------------------------------
// Kernel 3: per-sample ragged top-k mean (exact; binary search on float bits;
// only reads logits[b][0:L], so rows skipped by gemm are never touched).
// ---------------------------------------------------------------------------
__global__ __launch_bounds__(256) void topk_mean(const float* __restrict__ logits,
                                                 const int* __restrict__ seq_len,
                                                 float* __restrict__ out) {
    __shared__ float vals[T_SEQ];
    __shared__ int redi[4];
    __shared__ float redf[4];
    const int b = blockIdx.x, t = threadIdx.x;
    const int lane = t & 63, wave = t >> 6;
    const int L = seq_len[b];
    const int k = (L >> 4) + 1;
    const float* p = logits + b * T_SEQ;
    for (int i = t; i < L; i += 256) vals[i] = p[i];
    __syncthreads();

    unsigned lo = 0u, hi = 0x3f800000u;  // (0, 1.0]
    while (lo < hi) {
        unsigned mid = lo + ((hi - lo + 1) >> 1);
        float thr = __uint_as_float(mid);
        int cnt = 0;
        for (int i = t; i < L; i += 256) cnt += (vals[i] >= thr) ? 1 : 0;
#pragma unroll
        for (int m = 32; m >= 1; m >>= 1) cnt += __shfl_xor(cnt, m);
        if (lane == 0) redi[wave] = cnt;
        __syncthreads();
        int total = redi[0] + redi[1] + redi[2] + redi[3];
        __syncthreads();
        if (total >= k) lo = mid; else hi = mid - 1;
    }
    const float thr = __uint_as_float(lo);

    int cnt = 0; float sum = 0.f;
    for (int i = t; i < L; i += 256) {
        float x = vals[i];
        if (x > thr) { cnt += 1; sum += x; }
    }
#pragma unroll
    for (int m = 32; m >= 1; m >>= 1) { cnt += __shfl_xor(cnt, m); sum += __shfl_xor(sum, m); }
    if (lane == 0) { redi[wave] = cnt; redf[wave] = sum; }
    __syncthreads();
    if (t == 0) {
        int cgt = redi[0] + redi[1] + redi[2] + redi[3];
        float sgt = redf[0] + redf[1] + redf[2] + redf[3];
        out[b] = (sgt + (float)(k - cgt) * thr) / (float)k;
    }
}

// ---------------------------------------------------------------------------
extern "C" void kernel_launch(void* const* d_in, const int* in_sizes, int n_in,
                              void* d_out, int out_size, void* d_ws, size_t ws_size,
                              hipStream_t stream) {
    const float* avf = (const float*)d_in[0];
    const float* W1  = (const float*)d_in[1];
    const float* b1  = (const float*)d_in[2];
    const float* W2  = (const float*)d_in[3];
    const float* b2  = (const float*)d_in[4];
    const float* W3  = (const float*)d_in[5];
    const float* b3  = (const float*)d_in[6];
    const int* seq_len = (const int*)d_in[7];
    float* out = (float*)d_out;

    char* ws = (char*)d_ws;
    bf16*  W1T    = (bf16*)ws;                            // 1 MB @ 0
    float* v      = (float*)(ws + (1 << 20));             // 513 floats
    float* logits = (float*)(ws + (1 << 20) + (1 << 16)); // 256 KB

    transpose_w1<<<dim3(32, 16), 256, 0, stream>>>(W1, W1T);
    make_v<<<1, 512, 0, stream>>>(W2, b2, W3, b3, v);
    gemm_fused<<<M_TOT / 64, 512, 0, stream>>>(avf, W1T, b1, v, seq_len, logits);
    topk_mean<<<NB, 256, 0, stream>>>(logits, seq_len, out);
}